// Round 12
// baseline (263.453 us; speedup 1.0000x reference)
//
#include <hip/hip_runtime.h>
#include <math.h>

#define B_   8
#define LQ_  1024
#define D_   256
#define NH_  8
#define DH_  32
#define LIN_ 13125

typedef __attribute__((ext_vector_type(4))) float f32x4;
typedef __attribute__((ext_vector_type(8))) short bf16x8;
typedef __attribute__((ext_vector_type(4))) short bf16x4;

__device__ __forceinline__ float4 f4add(float4 a, float4 b){
  return make_float4(a.x+b.x, a.y+b.y, a.z+b.z, a.w+b.w);
}
__device__ __forceinline__ unsigned short f2bf(float f){
  unsigned u = __float_as_uint(f);
  unsigned r = (u + 0x7fffu + ((u>>16)&1u)) >> 16;
  return (unsigned short)r;
}
__device__ __forceinline__ float bf2f(unsigned short u){
  return __uint_as_float(((unsigned)u)<<16);
}
__device__ __forceinline__ unsigned pk2(float a, float b){
  return (unsigned)f2bf(a) | ((unsigned)f2bf(b)<<16);
}
__device__ __forceinline__ float fexp2(float x){
#if __has_builtin(__builtin_amdgcn_exp2f)
  return __builtin_amdgcn_exp2f(x);
#else
  return exp2f(x);
#endif
}
__device__ __forceinline__ f32x4 mfma16x16(bf16x4 a, bf16x4 b, f32x4 c){
#if __has_builtin(__builtin_amdgcn_mfma_f32_16x16x16_bf16)
  return __builtin_amdgcn_mfma_f32_16x16x16_bf16(a, b, c, 0, 0, 0);
#else
  asm volatile("s_nop 1\n\tv_mfma_f32_16x16x16_bf16 %0, %1, %2, %0"
               : "+v"(c) : "v"(a), "v"(b));
  return c;
#endif
}
__device__ __forceinline__ void gload16(const void* g, void* l){
  __builtin_amdgcn_global_load_lds(
      (const __attribute__((address_space(1))) void*)g,
      (__attribute__((address_space(3))) void*)l, 16, 0, 0);
}
__device__ __forceinline__ bf16x8 cvt8(const float4& a, const float4& b){
  unsigned u0,u1,u2,u3;
  asm("v_cvt_pk_bf16_f32 %0, %1, %2" : "=v"(u0) : "v"(a.x), "v"(a.y));
  asm("v_cvt_pk_bf16_f32 %0, %1, %2" : "=v"(u1) : "v"(a.z), "v"(a.w));
  asm("v_cvt_pk_bf16_f32 %0, %1, %2" : "=v"(u2) : "v"(b.x), "v"(b.y));
  asm("v_cvt_pk_bf16_f32 %0, %1, %2" : "=v"(u3) : "v"(b.z), "v"(b.w));
  uint4 uu = make_uint4(u0,u1,u2,u3);
  return __builtin_bit_cast(bf16x8, uu);
}
// bijective chunked XCD swizzle (m204)
__device__ __forceinline__ int xcd_swz(int lin, int nwg){
  if (nwg < 64) return lin;
  const int q = nwg >> 3, r = nwg & 7;
  const int x = lin & 7, d = lin >> 3;
  return (x < r ? x*(q+1) : r*(q+1) + (x-r)*q) + d;
}

// ---------------- elementwise prep (+ bias-table fills) ----------------
__global__ __launch_bounds__(256) void k_prep(
    const float4* __restrict__ qe, const float4* __restrict__ rf,
    const float4* __restrict__ qo, const float4* __restrict__ rp,
    const unsigned char* __restrict__ mask,
    const float* __restrict__ off_b, const float* __restrict__ att_b,
    float4* __restrict__ src, uint2* __restrict__ srcb, uint2* __restrict__ qb,
    float* __restrict__ biasf, float* __restrict__ biasoa)
{
  int i = blockIdx.x*256 + threadIdx.x;
  if (i < B_*LQ_) biasf[i] = mask[i] ? -2.0e9f : 0.f;
  if (blockIdx.x == 32) {
    for (int j = threadIdx.x; j < 384; j += 256)
      biasoa[j] = (j < 192) ? off_b[j] : (j < 288 ? att_b[j-192] : 0.f);
  }
  float4 s = f4add(qe[i], rf[i]);
  src[i] = s;
  float4 q = f4add(s, f4add(qo[i], rp[i]));
  srcb[i] = make_uint2(pk2(s.x,s.y), pk2(s.z,s.w));
  qb[i]   = make_uint2(pk2(q.x,q.y), pk2(q.z,q.w));
}

// ---------------- batched weight transpose->bf16: Wt[N][K] from W[K][N] ----------------
struct WEnt { const float* s; unsigned short* d; int K; int N; };
struct WPack { WEnt e[10]; };
__global__ __launch_bounds__(256) void k_wtcvt(WPack p)
{
  __shared__ float sm[32][33];
  WEnt w = p.e[blockIdx.y];
  const int tk = w.K >> 5, tn = w.N >> 5;
  const int nt = tk * tn;
  const int r = threadIdx.x >> 5, c = threadIdx.x & 31;
  for (int tile = blockIdx.x; tile < nt; tile += gridDim.x) {
    const int ti = tile / tn, tj = tile % tn;
    #pragma unroll
    for (int rr = r; rr < 32; rr += 8)
      sm[rr][c] = w.s[(size_t)(ti*32+rr)*w.N + tj*32 + c];
    __syncthreads();
    #pragma unroll
    for (int rr = r; rr < 32; rr += 8)
      w.d[(size_t)(tj*32+rr)*w.K + ti*32 + c] = f2bf(sm[c][rr]);
    __syncthreads();
  }
}

// ---------------- bf16 MFMA GEMM, 128x128 tile (large GEMMs) ----------------
template<bool BF16OUT>
__global__ __launch_bounds__(256) void k_gemm_bf(
    const unsigned short* __restrict__ A, int lda,
    const unsigned short* __restrict__ Wt,
    const float* __restrict__ bias,
    float* __restrict__ Cf, unsigned short* __restrict__ Cb, int ldc,
    int M, int N, int K, int relu)
{
  __shared__ unsigned short As[2][4096];
  __shared__ unsigned short Bs[2][4096];
  const int t = threadIdx.x;
  const int lin = xcd_swz(blockIdx.y*gridDim.x + blockIdx.x, gridDim.x*gridDim.y);
  const int bx = lin % gridDim.x, by = lin / gridDim.x;
  const int m0 = by * 128;
  const int n0 = bx * 128;
  const int w  = t >> 6, lane = t & 63;
  const int lr = lane & 15, lg = lane >> 4;
  const int wm = (w & 1) * 64, wn = (w >> 1) * 64;

  const int rowc  = t >> 2;
  const int cbs8  = (((t & 3) ^ ((t >> 2) & 3)) << 3);
  const size_t ra0 = (size_t)min(m0 + rowc,      M-1) * lda;
  const size_t ra1 = (size_t)min(m0 + rowc + 64, M-1) * lda;
  const size_t rb0 = (size_t)(n0 + rowc)      * K;
  const size_t rb1 = (size_t)(n0 + rowc + 64) * K;
  unsigned short* la0[2] = { &As[0][(w<<9)],        &As[1][(w<<9)] };
  unsigned short* la1[2] = { &As[0][2048+(w<<9)],   &As[1][2048+(w<<9)] };
  unsigned short* lb0[2] = { &Bs[0][(w<<9)],        &Bs[1][(w<<9)] };
  unsigned short* lb1[2] = { &Bs[0][2048+(w<<9)],   &Bs[1][2048+(w<<9)] };

  f32x4 acc[4][4];
  #pragma unroll
  for (int i=0;i<4;++i)
    #pragma unroll
    for (int j=0;j<4;++j) acc[i][j] = (f32x4){0.f,0.f,0.f,0.f};

  const int cswz = ((lg ^ (lr & 3)) << 3);
  const int nt = K >> 5;

  {
    gload16(A  + ra0 + cbs8, la0[0]);
    gload16(A  + ra1 + cbs8, la1[0]);
    gload16(Wt + rb0 + cbs8, lb0[0]);
    gload16(Wt + rb1 + cbs8, lb1[0]);
  }
  for (int ks = 0; ks < nt; ++ks) {
    const int cur = ks & 1;
    __syncthreads();
    if (ks + 1 < nt) {
      const int kb = (ks + 1) << 5;
      const int nb = cur ^ 1;
      gload16(A  + ra0 + kb + cbs8, la0[nb]);
      gload16(A  + ra1 + kb + cbs8, la1[nb]);
      gload16(Wt + rb0 + kb + cbs8, lb0[nb]);
      gload16(Wt + rb1 + kb + cbs8, lb1[nb]);
    }
    bf16x8 af[4], bfr[4];
    #pragma unroll
    for (int mi=0;mi<4;++mi)
      af[mi]  = *reinterpret_cast<const bf16x8*>(&As[cur][(wm+mi*16+lr)*32 + cswz]);
    #pragma unroll
    for (int ni=0;ni<4;++ni)
      bfr[ni] = *reinterpret_cast<const bf16x8*>(&Bs[cur][(wn+ni*16+lr)*32 + cswz]);
    #pragma unroll
    for (int mi=0;mi<4;++mi)
      #pragma unroll
      for (int ni=0;ni<4;++ni)
        acc[mi][ni] = __builtin_amdgcn_mfma_f32_16x16x32_bf16(af[mi], bfr[ni], acc[mi][ni], 0, 0, 0);
  }

  float bs[4];
  #pragma unroll
  for (int ni=0;ni<4;++ni) bs[ni] = bias[n0 + wn + ni*16 + lr];
  #pragma unroll
  for (int mi=0;mi<4;++mi){
    #pragma unroll
    for (int i=0;i<4;++i){
      const int row = m0 + wm + mi*16 + lg*4 + i;
      if (row >= M) continue;
      #pragma unroll
      for (int ni=0;ni<4;++ni){
        const int col = n0 + wn + ni*16 + lr;
        float v = acc[mi][ni][i] + bs[ni];
        if (relu) v = fmaxf(v, 0.f);
        if (BF16OUT) Cb[(size_t)row*ldc + col] = f2bf(v);
        else         Cf[(size_t)row*ldc + col] = v;
      }
    }
  }
}

// ---------------- value-projection GEMM: W in registers, no LDS, no barriers ----------------
// Each wave: 64 cols x 128 rows. W frags (kk=8 x ni=4) loaded once from global (L2-hit).
// A streamed as 8 slices of 16 rows: cvt -> issue-next-loads -> 32 MFMA. Fully independent waves.
__global__ __launch_bounds__(256) void k_gemm_vp(
    const float* __restrict__ A,            // fp32 (M,256)
    const unsigned short* __restrict__ Wt,  // bf16 [256][256]
    const float* __restrict__ bias,
    unsigned short* __restrict__ Cb, int M)
{
  const int t = threadIdx.x;
  const int lin = xcd_swz(blockIdx.y*gridDim.x + blockIdx.x, gridDim.x*gridDim.y);
  const int bx = lin % gridDim.x, by = lin / gridDim.x;
  const int w = t >> 6, lane = t & 63;
  const int lr = lane & 15, lg = lane >> 4;
  const int cw  = bx * 128 + (w & 1) * 64;      // wave col base
  const int mwv = by * 256 + (w >> 1) * 128;    // wave row base

  // W fragments -> registers (32 x 16B loads, L2-resident weights)
  bf16x8 wf[8][4];
  #pragma unroll
  for (int kk=0;kk<8;++kk)
    #pragma unroll
    for (int ni=0;ni<4;++ni)
      wf[kk][ni] = *reinterpret_cast<const bf16x8*>(
          Wt + (size_t)(cw + ni*16 + lr)*256 + kk*32 + lg*8);

  float bs[4];
  #pragma unroll
  for (int ni=0;ni<4;++ni) bs[ni] = bias[cw + ni*16 + lr];

  // prologue: load slice 0
  float4 av[8][2];
  {
    const size_t r0 = (size_t)min(mwv + lr, M-1)*256;
    #pragma unroll
    for (int kk=0;kk<8;++kk){
      av[kk][0] = *reinterpret_cast<const float4*>(A + r0 + kk*32 + lg*8);
      av[kk][1] = *reinterpret_cast<const float4*>(A + r0 + kk*32 + lg*8 + 4);
    }
  }
  #pragma unroll
  for (int s = 0; s < 8; ++s) {
    const int mb = mwv + s*16;
    // convert current slice (waits on loads)
    bf16x8 af[8];
    #pragma unroll
    for (int kk=0;kk<8;++kk) af[kk] = cvt8(av[kk][0], av[kk][1]);
    // issue next slice's loads into freed av regs
    if (s < 7) {
      const size_t rn = (size_t)min(mb + 16 + lr, M-1)*256;
      #pragma unroll
      for (int kk=0;kk<8;++kk){
        av[kk][0] = *reinterpret_cast<const float4*>(A + rn + kk*32 + lg*8);
        av[kk][1] = *reinterpret_cast<const float4*>(A + rn + kk*32 + lg*8 + 4);
      }
    }
    // compute: 32 MFMA, all operands in registers
    f32x4 acc[4];
    #pragma unroll
    for (int ni=0;ni<4;++ni) acc[ni] = (f32x4){0.f,0.f,0.f,0.f};
    #pragma unroll
    for (int kk=0;kk<8;++kk)
      #pragma unroll
      for (int ni=0;ni<4;++ni)
        acc[ni] = __builtin_amdgcn_mfma_f32_16x16x32_bf16(af[kk], wf[kk][ni], acc[ni], 0, 0, 0);
    #pragma unroll
    for (int ni=0;ni<4;++ni){
      const int col = cw + ni*16 + lr;
      #pragma unroll
      for (int i=0;i<4;++i){
        const int row = mb + lg*4 + i;
        if (row < M) Cb[(size_t)row*256 + col] = f2bf(acc[ni][i] + bs[ni]);
      }
    }
  }
}

// ---------------- bf16 MFMA GEMM, 64x64 tile, BK=64 ----------------
// EPI: 0 = f32 out, 1 = bf16 out, 2 = QK headwise bf16, 3 = V^T head layout
template<int EPI>
__global__ __launch_bounds__(256) void k_gemm64(
    const unsigned short* __restrict__ A, int lda,
    const unsigned short* __restrict__ Wt,
    const float* __restrict__ bias,
    float* __restrict__ Cf, unsigned short* __restrict__ Cb, int ldc,
    int M, int N, int K, int relu)
{
  __shared__ unsigned short As[2][4096];
  __shared__ unsigned short Bs[2][4096];
  const int t = threadIdx.x;
  const int lin = xcd_swz(blockIdx.y*gridDim.x + blockIdx.x, gridDim.x*gridDim.y);
  const int bx = lin % gridDim.x, by = lin / gridDim.x;
  const int m0 = by * 64;
  const int n0 = bx * 64;
  const int w = t >> 6, lane = t & 63;
  const int lr = lane & 15, lg = lane >> 4;
  const int wm = (w & 1) * 32, wn = (w >> 1) * 32;

  const int c0 = w*64 + lane;
  const int c1 = 256 + w*64 + lane;
  const int r0c = c0 >> 3, s0c = ((c0 & 7) ^ (r0c & 7)) << 3;
  const int r1c = c1 >> 3, s1c = ((c1 & 7) ^ (r1c & 7)) << 3;
  const size_t a0 = (size_t)(m0 + r0c)*lda + s0c;
  const size_t a1 = (size_t)(m0 + r1c)*lda + s1c;
  const size_t b0 = (size_t)(n0 + r0c)*K + s0c;
  const size_t b1 = (size_t)(n0 + r1c)*K + s1c;
  const int d0 = w*512, d1 = 2048 + w*512;

  f32x4 acc[2][2];
  acc[0][0]=acc[0][1]=acc[1][0]=acc[1][1]=(f32x4){0.f,0.f,0.f,0.f};

  gload16(A + a0, &As[0][d0]);  gload16(A + a1, &As[0][d1]);
  gload16(Wt + b0, &Bs[0][d0]); gload16(Wt + b1, &Bs[0][d1]);
  const int nt = K >> 6;
  for (int ks = 0; ks < nt; ++ks) {
    const int cur = ks & 1;
    __syncthreads();
    if (ks + 1 < nt) {
      const int kb = (ks + 1) << 6;
      const int nb = cur ^ 1;
      gload16(A + kb + a0, &As[nb][d0]);  gload16(A + kb + a1, &As[nb][d1]);
      gload16(Wt + kb + b0, &Bs[nb][d0]); gload16(Wt + kb + b1, &Bs[nb][d1]);
    }
    bf16x8 af[2][2], bfr[2][2];
    #pragma unroll
    for (int mi=0;mi<2;++mi){
      const int r = wm + mi*16 + lr;
      #pragma unroll
      for (int kk=0;kk<2;++kk){
        const int ch = ((kk*4 + lg) ^ (r & 7)) << 3;
        af[mi][kk] = *reinterpret_cast<const bf16x8*>(&As[cur][r*64 + ch]);
      }
    }
    #pragma unroll
    for (int ni=0;ni<2;++ni){
      const int r = wn + ni*16 + lr;
      #pragma unroll
      for (int kk=0;kk<2;++kk){
        const int ch = ((kk*4 + lg) ^ (r & 7)) << 3;
        bfr[ni][kk] = *reinterpret_cast<const bf16x8*>(&Bs[cur][r*64 + ch]);
      }
    }
    #pragma unroll
    for (int kk=0;kk<2;++kk)
      #pragma unroll
      for (int mi=0;mi<2;++mi)
        #pragma unroll
        for (int ni=0;ni<2;++ni)
          acc[mi][ni] = __builtin_amdgcn_mfma_f32_16x16x32_bf16(af[mi][kk], bfr[ni][kk], acc[mi][ni], 0, 0, 0);
  }

  float bs[2];
  bs[0] = bias[n0 + wn + lr];
  bs[1] = bias[n0 + wn + 16 + lr];
  if (EPI == 3) {
    #pragma unroll
    for (int mi=0;mi<2;++mi){
      const int rowb = m0 + wm + mi*16 + lg*4;
      #pragma unroll
      for (int ni=0;ni<2;++ni){
        const int colb = n0 + wn + ni*16 + lr;
        const int bh = (rowb >> 10)*8 + (colb >> 5);
        const int d = colb & 31;
        ushort4 pkv;
        pkv.x = f2bf(acc[mi][ni][0] + bs[ni]);
        pkv.y = f2bf(acc[mi][ni][1] + bs[ni]);
        pkv.z = f2bf(acc[mi][ni][2] + bs[ni]);
        pkv.w = f2bf(acc[mi][ni][3] + bs[ni]);
        *reinterpret_cast<ushort4*>(Cb + (size_t)bh*32768 + (size_t)d*1024 + (rowb & 1023)) = pkv;
      }
    }
    return;
  }
  #pragma unroll
  for (int mi=0;mi<2;++mi){
    #pragma unroll
    for (int i=0;i<4;++i){
      const int row = m0 + wm + mi*16 + lg*4 + i;
      #pragma unroll
      for (int ni=0;ni<2;++ni){
        const int col = n0 + wn + ni*16 + lr;
        float v = acc[mi][ni][i] + bs[ni];
        if (relu) v = fmaxf(v, 0.f);
        if (EPI == 0) {
          Cf[(size_t)row*ldc + col] = v;
        } else if (EPI == 1) {
          Cb[(size_t)row*ldc + col] = f2bf(v);
        } else {
          const int ch = col & 255;
          const int sel = col >> 8;                       // 0=Q, 1=K
          const int bh = (row >> 10)*8 + (ch >> 5);
          Cb[(size_t)sel*2097152 + (size_t)bh*32768 + (size_t)(row & 1023)*32 + (ch & 31)] = f2bf(v);
        }
      }
    }
  }
}

// ---------------- fused GEMM(N=256) + bias + residual + LayerNorm ----------------
__global__ __launch_bounds__(256) void k_gemm_ln(
    const unsigned short* __restrict__ A, int lda,
    const unsigned short* __restrict__ Wt,
    const float* __restrict__ bias,
    const float* __restrict__ X,
    const float* __restrict__ g, const float* __restrict__ be,
    float* __restrict__ out,
    unsigned short* __restrict__ ab,
    const float* __restrict__ qo, const float* __restrict__ rp,
    const float* __restrict__ rf, unsigned short* __restrict__ dqb,
    int K)
{
  __shared__ unsigned short As[2][1024];
  __shared__ unsigned short Bs[2][16384];
  __shared__ float part[4][16][2];
  const int t = threadIdx.x;
  const int w = t >> 6, lane = t & 63;
  const int lr = lane & 15, lg = lane >> 4;
  const int m0 = xcd_swz(blockIdx.x, gridDim.x) * 16;

  const int ar = t >> 3, ac = t & 7;
  const size_t aSrc = (size_t)(m0 + ar)*lda + ((ac ^ (ar & 7)) << 3);
  size_t bSrc[8];
  #pragma unroll
  for (int q=0;q<8;++q){
    const int c = q*256 + t;
    const int br = c >> 3, bc = c & 7;
    bSrc[q] = (size_t)br*K + ((bc ^ (br & 7)) << 3);
  }

  f32x4 acc[4];
  #pragma unroll
  for (int ni=0;ni<4;++ni) acc[ni] = (f32x4){0.f,0.f,0.f,0.f};

  if (w < 2) gload16(A + aSrc, &As[0][(w<<9)]);
  #pragma unroll
  for (int q=0;q<8;++q) gload16(Wt + bSrc[q], &Bs[0][q*2048 + (w<<9)]);

  const int nt = K >> 6;
  for (int ks = 0; ks < nt; ++ks) {
    const int cur = ks & 1;
    __syncthreads();
    if (ks + 1 < nt) {
      const int kb = (ks + 1) << 6;
      const int nb = cur ^ 1;
      if (w < 2) gload16(A + kb + aSrc, &As[nb][(w<<9)]);
      #pragma unroll
      for (int q=0;q<8;++q) gload16(Wt + kb + bSrc[q], &Bs[nb][q*2048 + (w<<9)]);
    }
    bf16x8 af[2];
    #pragma unroll
    for (int kk=0;kk<2;++kk){
      const int ch = ((kk*4 + lg) ^ (lr & 7)) << 3;
      af[kk] = *reinterpret_cast<const bf16x8*>(&As[cur][lr*64 + ch]);
    }
    #pragma unroll
    for (int ni=0;ni<4;++ni){
      const int r = w*64 + ni*16 + lr;
      #pragma unroll
      for (int kk=0;kk<2;++kk){
        const int ch = ((kk*4 + lg) ^ (r & 7)) << 3;
        bf16x8 bfv = *reinterpret_cast<const bf16x8*>(&Bs[cur][r*64 + ch]);
        acc[ni] = __builtin_amdgcn_mfma_f32_16x16x32_bf16(af[kk], bfv, acc[ni], 0, 0, 0);
      }
    }
  }

  float v[4][4];
  int colv[4];
  #pragma unroll
  for (int ni=0;ni<4;++ni) colv[ni] = w*64 + ni*16 + lr;
  #pragma unroll
  for (int ni=0;ni<4;++ni){
    const float bsv = bias[colv[ni]];
    #pragma unroll
    for (int i=0;i<4;++i){
      const int row = m0 + lg*4 + i;
      v[ni][i] = acc[ni][i] + bsv + X[(size_t)row*256 + colv[ni]];
    }
  }
  #pragma unroll
  for (int i=0;i<4;++i){
    float s1 = v[0][i]+v[1][i]+v[2][i]+v[3][i];
    float s2 = v[0][i]*v[0][i]+v[1][i]*v[1][i]+v[2][i]*v[2][i]+v[3][i]*v[3][i];
    #pragma unroll
    for (int o=1;o<16;o<<=1){ s1 += __shfl_xor(s1,o,64); s2 += __shfl_xor(s2,o,64); }
    if (lr == 0){ part[w][lg*4+i][0] = s1; part[w][lg*4+i][1] = s2; }
  }
  __syncthreads();
  #pragma unroll
  for (int i=0;i<4;++i){
    const int rl = lg*4 + i;
    const float S1 = part[0][rl][0]+part[1][rl][0]+part[2][rl][0]+part[3][rl][0];
    const float S2 = part[0][rl][1]+part[1][rl][1]+part[2][rl][1]+part[3][rl][1];
    const float mean = S1 * 0.00390625f;
    const float var  = S2 * 0.00390625f - mean*mean;
    const float rstd = rsqrtf(var + 1e-5f);
    const size_t row = m0 + rl;
    #pragma unroll
    for (int ni=0;ni<4;++ni){
      const int col = colv[ni];
      const float o = (v[ni][i]-mean)*rstd*g[col] + be[col];
      out[row*256 + col] = o;
      if (ab) ab[row*256 + col] = f2bf(o);
      if (dqb) {
        const float e = qo[row*256+col] + rp[row*256+col] + rf[row*256+col];
        dqb[row*256 + col] = f2bf(o + e);
      }
    }
  }
}

// ---------------- MFMA flash attention, LDS-staged double-buffered, XCD-swizzled ----------------
__global__ __launch_bounds__(256) void k_attn2(
    const unsigned short* __restrict__ Qbf,
    const unsigned short* __restrict__ Kbf,
    const unsigned short* __restrict__ Vtb,
    const float* __restrict__ biasf,
    unsigned short* __restrict__ Ob)
{
  __shared__ unsigned short Klds[2][2048];
  __shared__ unsigned short Vlds[2][2048];
  __shared__ float Blds[1024];
  const int t = threadIdx.x;
  const int wv = t >> 6, lane = t & 63;
  const int lin = xcd_swz(blockIdx.y*gridDim.x + blockIdx.x, gridDim.x*gridDim.y);
  const int bx = lin % gridDim.x, by = lin / gridDim.x;
  const int qt = bx * 4 + wv;
  const int bh = by;
  const int b = bh >> 3;
  const int q0 = qt << 4;
  const int lr = lane & 15, lg = lane >> 4;

  bf16x8 qf = *reinterpret_cast<const bf16x8*>(
      Qbf + (size_t)bh*32768 + (size_t)(q0 + lr)*32 + lg*8);

  *reinterpret_cast<float4*>(&Blds[t*4]) =
      *reinterpret_cast<const float4*>(biasf + b*1024 + t*4);

  const unsigned short* Kg = Kbf + (size_t)bh*32768;
  const unsigned short* Vg = Vtb + (size_t)bh*32768;

  const int kRow   = lane >> 2;
  const int kChunk = (lane & 3) ^ (kRow & 3);
  const size_t kSrc = (size_t)(wv*16 + kRow)*32 + (kChunk<<3);
  const int vDim   = lane >> 3;
  const int vChunk = (lane & 7) ^ vDim;
  const size_t vSrc = (size_t)(wv*8 + vDim)*1024 + (vChunk<<3);
  unsigned short* kDst[2] = { &Klds[0][wv<<9], &Klds[1][wv<<9] };
  unsigned short* vDst[2] = { &Vlds[0][wv<<9], &Vlds[1][wv<<9] };

  gload16(Kg + kSrc, kDst[0]);
  gload16(Vg + vSrc, vDst[0]);
  __syncthreads();

  f32x4 acc0 = {0.f,0.f,0.f,0.f}, acc1 = {0.f,0.f,0.f,0.f};
  float m_run = -1e30f, l_run = 0.f;
  const float Cs = 0.17677669529663687f * 1.4426950408889634f;
  const int kswz = (lg ^ (lr & 3)) << 3;

  for (int kt = 0; kt < 16; ++kt) {
    const int cur = kt & 1;
    if (kt + 1 < 16) {
      const size_t k0n = (size_t)(kt + 1) << 6;
      gload16(Kg + k0n*32 + kSrc, kDst[cur^1]);
      gload16(Vg + k0n    + vSrc, vDst[cur^1]);
    }
    f32x4 st[4];
    __builtin_amdgcn_s_setprio(1);
    #pragma unroll
    for (int j=0;j<4;++j){
      bf16x8 kf = *reinterpret_cast<const bf16x8*>(&Klds[cur][(16*j + lr)*32 + kswz]);
      f32x4 z = {0.f,0.f,0.f,0.f};
      st[j] = __builtin_amdgcn_mfma_f32_16x16x32_bf16(kf, qf, z, 0, 0, 0);
    }
    __builtin_amdgcn_s_setprio(0);
    const int k0 = kt << 6;
    float s[16];
    #pragma unroll
    for (int j=0;j<4;++j){
      float4 bv = *reinterpret_cast<const float4*>(&Blds[k0 + 16*j + lg*4]);
      s[4*j+0] = fmaf(st[j][0], Cs, bv.x);
      s[4*j+1] = fmaf(st[j][1], Cs, bv.y);
      s[4*j+2] = fmaf(st[j][2], Cs, bv.z);
      s[4*j+3] = fmaf(st[j][3], Cs, bv.w);
    }
    float mc = fmaxf(fmaxf(fmaxf(s[0],s[1]),fmaxf(s[2],s[3])),
                     fmaxf(fmaxf(s[4],s[5]),fmaxf(s[6],s[7])));
    float mc2 = fmaxf(fmaxf(fmaxf(s[8],s[9]),fmaxf(s[10],s[11])),
                      fmaxf(fmaxf(s[12],s[13]),fmaxf(s[14],s[15])));
    mc = fmaxf(mc, mc2);
    mc = fmaxf(mc, __shfl_xor(mc, 16, 64));
    mc = fmaxf(mc, __shfl_xor(mc, 32, 64));
    if (!__all(mc <= m_run + 8.f)) {
      float m_new = fmaxf(m_run, mc);
      float sc = fexp2(m_run - m_new);
      l_run *= sc;
      m_run = m_new;
      float sc0 = __shfl(sc, lg*4+0, 64);
      float sc1 = __shfl(sc, lg*4+1, 64);
      float sc2 = __shfl(sc, lg*4+2, 64);
      float sc3 = __shfl(sc, lg*4+3, 64);
      acc0[0]*=sc0; acc0[1]*=sc1; acc0[2]*=sc2; acc0[3]*=sc3;
      acc1[0]*=sc0; acc1[1]*=sc1; acc1[2]*=sc2; acc1[3]*=sc3;
    }
    float p[16];
    #pragma unroll
    for (int i=0;i<16;++i) p[i] = fexp2(s[i] - m_run);
    float ps = 0.f;
    #pragma unroll
    for (int i=0;i<16;++i) ps += p[i];
    ps += __shfl_xor(ps, 16, 64);
    ps += __shfl_xor(ps, 32, 64);
    l_run += ps;
    bf16x4 pb[4];
    #pragma unroll
    for (int j=0;j<4;++j){
      unsigned lo, hi;
      asm("v_cvt_pk_bf16_f32 %0, %1, %2" : "=v"(lo) : "v"(p[4*j+0]), "v"(p[4*j+1]));
      asm("v_cvt_pk_bf16_f32 %0, %1, %2" : "=v"(hi) : "v"(p[4*j+2]), "v"(p[4*j+3]));
      uint2 u = make_uint2(lo, hi);
      pb[j] = __builtin_bit_cast(bf16x4, u);
    }
    __builtin_amdgcn_s_setprio(1);
    #pragma unroll
    for (int j=0;j<4;++j){
      const int coff = (((2*j + (lg>>1)) ^ (lr & 7)) << 3) + ((lg & 1) << 2);
      bf16x4 v0 = *reinterpret_cast<const bf16x4*>(&Vlds[cur][lr*64 + coff]);
      bf16x4 v1 = *reinterpret_cast<const bf16x4*>(&Vlds[cur][(16+lr)*64 + coff]);
      acc0 = mfma16x16(pb[j], v0, acc0);
      acc1 = mfma16x16(pb[j], v1, acc1);
    }
    __builtin_amdgcn_s_setprio(0);
    __syncthreads();
  }
  float li[4];
  #pragma unroll
  for (int i=0;i<4;++i) li[i] = 1.f / __shfl(l_run, lg*4+i, 64);
  const int h = bh & 7;
  unsigned short* orow = Ob + (size_t)(b*1024 + q0)*256 + h*32;
  #pragma unroll
  for (int i=0;i<4;++i){
    orow[(size_t)(lg*4+i)*256 + lr]      = f2bf(acc0[i]*li[i]);
    orow[(size_t)(lg*4+i)*256 + 16 + lr] = f2bf(acc1[i]*li[i]);
  }
}

// ---------------- deform: fused weights + gather (one block per bq) ----------------
__global__ __launch_bounds__(256) void k_dgather2(
    const unsigned short* __restrict__ vproj,
    const float* __restrict__ IJ,
    const float* __restrict__ refp,
    unsigned short* __restrict__ outb)
{
  __shared__ int   ilds[8][12][4];
  __shared__ float wlds[8][12][4];
  const int t = threadIdx.x;
  const int bq = blockIdx.x;
  const int h = t >> 5;
  const int p = t & 31;
  if (p < 12) {
    const float* al = IJ + (size_t)bq*384 + 192 + h*12;
    float lg[12];
    float mx = -INFINITY;
    #pragma unroll
    for (int i=0;i<12;++i){ lg[i] = al[i]; mx = fmaxf(mx, lg[i]); }
    float se = 0.f;
    #pragma unroll
    for (int i=0;i<12;++i) se += __expf(lg[i]-mx);
    const float aw = __expf(lg[p]-mx) / se;
    const float rx = refp[(size_t)bq*2+0], ry = refp[(size_t)bq*2+1];
    const float ox = IJ[(size_t)bq*384 + h*24 + 2*p];
    const float oy = IJ[(size_t)bq*384 + h*24 + 2*p + 1];
    const int l = p >> 2;
    const int WW[3]={100,50,25}, SS[3]={0,10000,12500};
    const int Wi = WW[l], Hi = WW[l], s0 = SS[l];
    const float Wf = (float)Wi, Hf = (float)Hi;
    const float x = (rx + ox/Wf)*Wf - 0.5f;
    const float y = (ry + oy/Hf)*Hf - 0.5f;
    const float x0f = floorf(x), y0f = floorf(y);
    const float wx = x - x0f, wy = y - y0f;
    const int x0 = (int)x0f, y0 = (int)y0f;
    const int xs0 = min(max(x0,0),Wi-1),   xs1 = min(max(x0+1,0),Wi-1);
    const int ys0 = min(max(y0,0),Hi-1),   ys1 = min(max(y0+1,0),Hi-1);
    const bool vx0 = (x0>=0)&&(x0<Wi),     vx1 = (x0+1>=0)&&(x0+1<Wi);
    const bool vy0 = (y0>=0)&&(y0<Hi),     vy1 = (y0+1>=0)&&(y0+1<Hi);
    const int vb = (bq >> 10) * LIN_;
    ilds[h][p][0] = vb + s0 + ys0*Wi + xs0;
    ilds[h][p][1] = vb + s0 + ys0*Wi + xs1;
    ilds[h][p][2] = vb + s0 + ys1*Wi + xs0;
    ilds[h][p][3] = vb + s0 + ys1*Wi + xs1;
    wlds[h][p][0] = (vy0&&vx0)? (1.f-wy)*(1.f-wx)*aw : 0.f;
    wlds[h][p][1] = (vy0&&vx1)? (1.f-wy)*wx*aw       : 0.f;
    wlds[h][p][2] = (vy1&&vx0)? wy*(1.f-wx)*aw       : 0.f;
    wlds[h][p][3] = (vy1&&vx1)? wy*wx*aw             : 0.f;
  }
  __syncthreads();
  const int col = t;
  float acc = 0.f;
  #pragma unroll
  for (int pt=0; pt<12; ++pt){
    acc = fmaf(wlds[h][pt][0], bf2f(vproj[(size_t)ilds[h][pt][0]*256 + col]), acc);
    acc = fmaf(wlds[h][pt][1], bf2f(vproj[(size_t)ilds[h][pt][1]*256 + col]), acc);
    acc = fmaf(wlds[h][pt][2], bf2f(vproj[(size_t)ilds[h][pt][2]*256 + col]), acc);
    acc = fmaf(wlds[h][pt][3], bf2f(vproj[(size_t)ilds[h][pt][3]*256 + col]), acc);
  }
  outb[(size_t)bq*256 + col] = f2bf(acc);
}

extern "C" void kernel_launch(void* const* d_in, const int* in_sizes, int n_in,
                              void* d_out, int out_size, void* d_ws, size_t ws_size,
                              hipStream_t stream)
{
  const float* qe      = (const float*)d_in[0];
  const unsigned char* qmask = (const unsigned char*)d_in[1];
  const float* qo      = (const float*)d_in[2];
  const float* values  = (const float*)d_in[3];
  const float* refp    = (const float*)d_in[4];
  const float* rp      = (const float*)d_in[5];
  const float* rf      = (const float*)d_in[6];
  const float* sa_in_w = (const float*)d_in[10];
  const float* sa_in_b = (const float*)d_in[11];
  const float* sa_out_w= (const float*)d_in[12];
  const float* sa_out_b= (const float*)d_in[13];
  const float* sa_ln1_g= (const float*)d_in[14];
  const float* sa_ln1_b= (const float*)d_in[15];
  const float* sa_l1_w = (const float*)d_in[16];
  const float* sa_l1_b = (const float*)d_in[17];
  const float* sa_l2_w = (const float*)d_in[18];
  const float* sa_l2_b = (const float*)d_in[19];
  const float* sa_ln2_g= (const float*)d_in[20];
  const float* sa_ln2_b= (const float*)d_in[21];
  const float* da_val_w= (const float*)d_in[22];
  const float* da_val_b= (const float*)d_in[23];
  const float* da_off_w= (const float*)d_in[24];
  const float* da_off_b= (const float*)d_in[25];
  const float* da_att_w= (const float*)d_in[26];
  const float* da_att_b= (const float*)d_in[27];
  const float* da_out_w= (const float*)d_in[28];
  const float* da_out_b= (const float*)d_in[29];
  const float* ln1_g   = (const float*)d_in[30];
  const float* ln1_b   = (const float*)d_in[31];
  const float* ff1_w   = (const float*)d_in[32];
  const float* ff1_b   = (const float*)d_in[33];
  const float* ff2_w   = (const float*)d_in[34];
  const float* ff2_b   = (const float*)d_in[35];
  const float* ln2_g   = (const float*)d_in[36];
  const float* ln2_b   = (const float*)d_in[37];

  float* Wk = (float*)d_ws;
  const size_t MEG = 1u<<20;
  float* A   = Wk;                                       // [0,2M)
  unsigned short* Ab   = (unsigned short*)(Wk + 4*MEG);  // [4M,5M)
  unsigned short* hidb = (unsigned short*)(Wk + 5*MEG);  // [5M,9M)
  unsigned short* WT   = (unsigned short*)(Wk + 9*MEG);  // [9M,10M)
  unsigned short* qb   = (unsigned short*)(Wk + 10*MEG); // [10M,11M)
  unsigned short* srcb = (unsigned short*)(Wk + 11*MEG); // [11M,12M)
  unsigned short* Qbf  = (unsigned short*)(Wk + 12*MEG); // [12M,13M)
  unsigned short* Kbf  = (unsigned short*)(Wk + 13*MEG); // [13M,14M) (= Qbf+2097152)
  unsigned short* Vtb  = (unsigned short*)(Wk + 15*MEG); // [15M,16M)
  unsigned short* aob  = (unsigned short*)(Wk + 16*MEG); // [16M,17M)
  // deform phase (reuses attn regions after they're dead)
  unsigned short* dqb  = (unsigned short*)(Wk + 10*MEG); // [10M,11M)
  float* IJ = Wk + 12*MEG;                               // 8192x384 f32
  unsigned short* Hb = (unsigned short*)(Wk + 37*MEG);   // vproj bf16
  unsigned short* dG = (unsigned short*)(Wk + 51*MEG);   // gather out bf16
  float* biasf  = Wk + 52*MEG;                           // 8192 f32
  float* biasoa = Wk + 52*MEG + 8192;                    // 384 f32

  unsigned short* sa_inT  = WT;
  unsigned short* sa_outT = WT + 196608;
  unsigned short* sa_l1T  = WT + 262144;
  unsigned short* sa_l2T  = WT + 524288;
  unsigned short* da_valT = WT + 786432;
  unsigned short* da_outT = WT + 851968;
  unsigned short* ff1T    = WT + 917504;
  unsigned short* ff2T    = WT + 1179648;
  unsigned short* offattT = WT + 1441792;                // 384x256 (rows 288+ garbage, never read)

  WPack wp_;
  wp_.e[0] = { sa_in_w, sa_inT, 256, 768 };
  wp_.e[1] = { sa_out_w, sa_outT, 256, 256 };
  wp_.e[2] = { sa_l1_w, sa_l1T, 256, 1024 };
  wp_.e[3] = { sa_l2_w, sa_l2T, 1024, 256 };
  wp_.e[4] = { da_val_w, da_valT, 256, 256 };
  wp_.e[5] = { da_out_w, da_outT, 256, 256 };
  wp_.e[6] = { ff1_w, ff1T, 256, 1024 };
  wp_.e[7] = { ff2_w, ff2T, 1024, 256 };
  wp_.e[8] = { da_off_w, offattT, 256, 192 };
  wp_.e[9] = { da_att_w, offattT + 192*256, 256, 96 };

  dim3 blk(256);
  k_wtcvt<<<dim3(64,10), blk, 0, stream>>>(wp_);
  k_prep<<<2048, blk, 0, stream>>>((const float4*)qe,(const float4*)rf,
                                   (const float4*)qo,(const float4*)rp,
                                   qmask, da_off_b, da_att_b,
                                   (float4*)A,(uint2*)srcb,(uint2*)qb,
                                   biasf, biasoa);
  k_gemm64<2><<<dim3(8,128), blk, 0, stream>>>(qb,256, sa_inT, sa_in_b, nullptr,Qbf,0, 8192,512,256, 0);
  k_gemm64<3><<<dim3(4,128), blk, 0, stream>>>(srcb,256, sa_inT+512*256, sa_in_b+512, nullptr,Vtb,0, 8192,256,256, 0);
  k_attn2<<<dim3(16,64), blk, 0, stream>>>(Qbf, Kbf, Vtb, biasf, aob);
  k_gemm_ln<<<512, blk, 0, stream>>>(aob,256, sa_outT, sa_out_b, A,
                                     sa_ln1_g, sa_ln1_b, A, Ab,
                                     nullptr, nullptr, nullptr, nullptr, 256);
  k_gemm_bf<true><<<dim3(8,64), blk, 0, stream>>>(Ab,256, sa_l1T, sa_l1_b, nullptr,hidb,1024, 8192,1024,256, 1);
  k_gemm_ln<<<512, blk, 0, stream>>>(hidb,1024, sa_l2T, sa_l2_b, A,
                                     sa_ln2_g, sa_ln2_b, A, Ab,
                                     qo, rp, rf, dqb, 1024);
  k_gemm64<0><<<dim3(6,128), blk, 0, stream>>>(dqb,256, offattT, biasoa, IJ,nullptr,384, 8192,384,256, 0);
  k_gemm_vp<<<dim3(2,411), blk, 0, stream>>>(values, da_valT, da_val_b, Hb, 105000);
  k_dgather2<<<8192, blk, 0, stream>>>(Hb, IJ, refp, dG);
  k_gemm_ln<<<512, blk, 0, stream>>>(dG,256, da_outT, da_out_b, A,
                                     ln1_g, ln1_b, A, Ab,
                                     nullptr, nullptr, nullptr, nullptr, 256);
  k_gemm_bf<true><<<dim3(8,64), blk, 0, stream>>>(Ab,256, ff1T, ff1_b, nullptr,hidb,1024, 8192,1024,256, 1);
  k_gemm_ln<<<512, blk, 0, stream>>>(hidb,1024, ff2T, ff2_b, A,
                                     ln2_g, ln2_b, (float*)d_out, nullptr,
                                     nullptr, nullptr, nullptr, nullptr, 1024);
}

// Round 13
// 219.840 us; speedup vs baseline: 1.1984x; 1.1984x over previous
//
#include <hip/hip_runtime.h>
#include <math.h>

#define B_   8
#define LQ_  1024
#define D_   256
#define NH_  8
#define DH_  32
#define LIN_ 13125

typedef __attribute__((ext_vector_type(4))) float f32x4;
typedef __attribute__((ext_vector_type(8))) short bf16x8;
typedef __attribute__((ext_vector_type(4))) short bf16x4;

__device__ __forceinline__ float4 f4add(float4 a, float4 b){
  return make_float4(a.x+b.x, a.y+b.y, a.z+b.z, a.w+b.w);
}
__device__ __forceinline__ unsigned short f2bf(float f){
  unsigned u = __float_as_uint(f);
  unsigned r = (u + 0x7fffu + ((u>>16)&1u)) >> 16;
  return (unsigned short)r;
}
__device__ __forceinline__ float bf2f(unsigned short u){
  return __uint_as_float(((unsigned)u)<<16);
}
__device__ __forceinline__ unsigned pk2(float a, float b){
  return (unsigned)f2bf(a) | ((unsigned)f2bf(b)<<16);
}
__device__ __forceinline__ float fexp2(float x){
#if __has_builtin(__builtin_amdgcn_exp2f)
  return __builtin_amdgcn_exp2f(x);
#else
  return exp2f(x);
#endif
}
__device__ __forceinline__ f32x4 mfma16x16(bf16x4 a, bf16x4 b, f32x4 c){
#if __has_builtin(__builtin_amdgcn_mfma_f32_16x16x16_bf16)
  return __builtin_amdgcn_mfma_f32_16x16x16_bf16(a, b, c, 0, 0, 0);
#else
  asm volatile("s_nop 1\n\tv_mfma_f32_16x16x16_bf16 %0, %1, %2, %0"
               : "+v"(c) : "v"(a), "v"(b));
  return c;
#endif
}
__device__ __forceinline__ void gload16(const void* g, void* l){
  __builtin_amdgcn_global_load_lds(
      (const __attribute__((address_space(1))) void*)g,
      (__attribute__((address_space(3))) void*)l, 16, 0, 0);
}
// bijective chunked XCD swizzle (m204)
__device__ __forceinline__ int xcd_swz(int lin, int nwg){
  if (nwg < 64) return lin;
  const int q = nwg >> 3, r = nwg & 7;
  const int x = lin & 7, d = lin >> 3;
  return (x < r ? x*(q+1) : r*(q+1) + (x-r)*q) + d;
}

// ---------------- elementwise prep (+ bias-table fills) ----------------
__global__ __launch_bounds__(256) void k_prep(
    const float4* __restrict__ qe, const float4* __restrict__ rf,
    const float4* __restrict__ qo, const float4* __restrict__ rp,
    const unsigned char* __restrict__ mask,
    const float* __restrict__ off_b, const float* __restrict__ att_b,
    float4* __restrict__ src, uint2* __restrict__ srcb, uint2* __restrict__ qb,
    float* __restrict__ biasf, float* __restrict__ biasoa)
{
  int i = blockIdx.x*256 + threadIdx.x;
  if (i < B_*LQ_) biasf[i] = mask[i] ? -2.0e9f : 0.f;
  if (blockIdx.x == 32) {
    for (int j = threadIdx.x; j < 384; j += 256)
      biasoa[j] = (j < 192) ? off_b[j] : (j < 288 ? att_b[j-192] : 0.f);
  }
  float4 s = f4add(qe[i], rf[i]);
  src[i] = s;
  float4 q = f4add(s, f4add(qo[i], rp[i]));
  srcb[i] = make_uint2(pk2(s.x,s.y), pk2(s.z,s.w));
  qb[i]   = make_uint2(pk2(q.x,q.y), pk2(q.z,q.w));
}

// ---------------- batched weight transpose->bf16: Wt[N][K] from W[K][N] ----------------
struct WEnt { const float* s; unsigned short* d; int K; int N; };
struct WPack { WEnt e[10]; };
__global__ __launch_bounds__(256) void k_wtcvt(WPack p)
{
  __shared__ float sm[32][33];
  WEnt w = p.e[blockIdx.y];
  const int tk = w.K >> 5, tn = w.N >> 5;
  const int nt = tk * tn;
  const int r = threadIdx.x >> 5, c = threadIdx.x & 31;
  for (int tile = blockIdx.x; tile < nt; tile += gridDim.x) {
    const int ti = tile / tn, tj = tile % tn;
    #pragma unroll
    for (int rr = r; rr < 32; rr += 8)
      sm[rr][c] = w.s[(size_t)(ti*32+rr)*w.N + tj*32 + c];
    __syncthreads();
    #pragma unroll
    for (int rr = r; rr < 32; rr += 8)
      w.d[(size_t)(tj*32+rr)*w.K + ti*32 + c] = f2bf(sm[c][rr]);
    __syncthreads();
  }
}

// ---------------- bf16 MFMA GEMM, 128x128 tile (large GEMMs) ----------------
template<bool BF16OUT>
__global__ __launch_bounds__(256) void k_gemm_bf(
    const unsigned short* __restrict__ A, int lda,
    const unsigned short* __restrict__ Wt,
    const float* __restrict__ bias,
    float* __restrict__ Cf, unsigned short* __restrict__ Cb, int ldc,
    int M, int N, int K, int relu)
{
  __shared__ unsigned short As[2][4096];
  __shared__ unsigned short Bs[2][4096];
  const int t = threadIdx.x;
  const int lin = xcd_swz(blockIdx.y*gridDim.x + blockIdx.x, gridDim.x*gridDim.y);
  const int bx = lin % gridDim.x, by = lin / gridDim.x;
  const int m0 = by * 128;
  const int n0 = bx * 128;
  const int w  = t >> 6, lane = t & 63;
  const int lr = lane & 15, lg = lane >> 4;
  const int wm = (w & 1) * 64, wn = (w >> 1) * 64;

  const int rowc  = t >> 2;
  const int cbs8  = (((t & 3) ^ ((t >> 2) & 3)) << 3);
  const size_t ra0 = (size_t)min(m0 + rowc,      M-1) * lda;
  const size_t ra1 = (size_t)min(m0 + rowc + 64, M-1) * lda;
  const size_t rb0 = (size_t)(n0 + rowc)      * K;
  const size_t rb1 = (size_t)(n0 + rowc + 64) * K;
  unsigned short* la0[2] = { &As[0][(w<<9)],        &As[1][(w<<9)] };
  unsigned short* la1[2] = { &As[0][2048+(w<<9)],   &As[1][2048+(w<<9)] };
  unsigned short* lb0[2] = { &Bs[0][(w<<9)],        &Bs[1][(w<<9)] };
  unsigned short* lb1[2] = { &Bs[0][2048+(w<<9)],   &Bs[1][2048+(w<<9)] };

  f32x4 acc[4][4];
  #pragma unroll
  for (int i=0;i<4;++i)
    #pragma unroll
    for (int j=0;j<4;++j) acc[i][j] = (f32x4){0.f,0.f,0.f,0.f};

  const int cswz = ((lg ^ (lr & 3)) << 3);
  const int nt = K >> 5;

  {
    gload16(A  + ra0 + cbs8, la0[0]);
    gload16(A  + ra1 + cbs8, la1[0]);
    gload16(Wt + rb0 + cbs8, lb0[0]);
    gload16(Wt + rb1 + cbs8, lb1[0]);
  }
  for (int ks = 0; ks < nt; ++ks) {
    const int cur = ks & 1;
    __syncthreads();
    if (ks + 1 < nt) {
      const int kb = (ks + 1) << 5;
      const int nb = cur ^ 1;
      gload16(A  + ra0 + kb + cbs8, la0[nb]);
      gload16(A  + ra1 + kb + cbs8, la1[nb]);
      gload16(Wt + rb0 + kb + cbs8, lb0[nb]);
      gload16(Wt + rb1 + kb + cbs8, lb1[nb]);
    }
    bf16x8 af[4], bfr[4];
    #pragma unroll
    for (int mi=0;mi<4;++mi)
      af[mi]  = *reinterpret_cast<const bf16x8*>(&As[cur][(wm+mi*16+lr)*32 + cswz]);
    #pragma unroll
    for (int ni=0;ni<4;++ni)
      bfr[ni] = *reinterpret_cast<const bf16x8*>(&Bs[cur][(wn+ni*16+lr)*32 + cswz]);
    #pragma unroll
    for (int mi=0;mi<4;++mi)
      #pragma unroll
      for (int ni=0;ni<4;++ni)
        acc[mi][ni] = __builtin_amdgcn_mfma_f32_16x16x32_bf16(af[mi], bfr[ni], acc[mi][ni], 0, 0, 0);
  }

  float bs[4];
  #pragma unroll
  for (int ni=0;ni<4;++ni) bs[ni] = bias[n0 + wn + ni*16 + lr];
  #pragma unroll
  for (int mi=0;mi<4;++mi){
    #pragma unroll
    for (int i=0;i<4;++i){
      const int row = m0 + wm + mi*16 + lg*4 + i;
      if (row >= M) continue;
      #pragma unroll
      for (int ni=0;ni<4;++ni){
        const int col = n0 + wn + ni*16 + lr;
        float v = acc[mi][ni][i] + bs[ni];
        if (relu) v = fmaxf(v, 0.f);
        if (BF16OUT) Cb[(size_t)row*ldc + col] = f2bf(v);
        else         Cf[(size_t)row*ldc + col] = v;
      }
    }
  }
}

// ---------------- value-projection GEMM: A fp32 in, fused cvt, bf16 out ----------------
// 128x128, BK=32; A staged raw fp32 (XOR-8 chunk swizzle), converted on ds_read.
// (round-8 configuration: best measured, total 225.7; vp plateau accepted)
__global__ __launch_bounds__(256) void k_gemm_vp(
    const float* __restrict__ A,            // fp32 (M,256)
    const unsigned short* __restrict__ Wt,  // bf16 [256][256]
    const float* __restrict__ bias,
    unsigned short* __restrict__ Cb, int M)
{
  __shared__ float Af[2][4096];             // 128 x 32 f32
  __shared__ unsigned short Bs[2][4096];    // 128 x 32 bf16
  const int t = threadIdx.x;
  const int lin = xcd_swz(blockIdx.y*gridDim.x + blockIdx.x, gridDim.x*gridDim.y);
  const int bx = lin % gridDim.x, by = lin / gridDim.x;
  const int m0 = by * 128, n0 = bx * 128;
  const int w = t >> 6, lane = t & 63;
  const int lr = lane & 15, lg = lane >> 4;
  const int wm = (w & 1) * 64, wn = (w >> 1) * 64;
  const int K = 256;

  size_t aSrc[4]; int aDst[4];
  #pragma unroll
  for (int q=0;q<4;++q){
    const int ch = q*256 + t;
    const int r = ch >> 3, cpos = ch & 7;
    aSrc[q] = (size_t)min(m0 + r, M-1)*256 + ((cpos ^ (r & 7)) << 2);
    aDst[q] = ch << 2;
  }
  const int rowc = t >> 2;
  const int cbs8 = (((t & 3) ^ ((t >> 2) & 3)) << 3);
  const size_t rb0 = (size_t)(n0 + rowc)      * K + cbs8;
  const size_t rb1 = (size_t)(n0 + rowc + 64) * K + cbs8;
  unsigned short* lb0[2] = { &Bs[0][(w<<9)],      &Bs[1][(w<<9)] };
  unsigned short* lb1[2] = { &Bs[0][2048+(w<<9)], &Bs[1][2048+(w<<9)] };

  f32x4 acc[4][4];
  #pragma unroll
  for (int i=0;i<4;++i)
    #pragma unroll
    for (int j=0;j<4;++j) acc[i][j] = (f32x4){0.f,0.f,0.f,0.f};

  const int cswz = ((lg ^ (lr & 3)) << 3);

  #pragma unroll
  for (int q=0;q<4;++q) gload16(A + aSrc[q], &Af[0][aDst[q]]);
  gload16(Wt + rb0, lb0[0]);
  gload16(Wt + rb1, lb1[0]);

  const int nt = K >> 5;  // 8
  for (int ks = 0; ks < nt; ++ks) {
    const int cur = ks & 1;
    __syncthreads();
    if (ks + 1 < nt) {
      const int kb = (ks + 1) << 5;
      const int nb = cur ^ 1;
      #pragma unroll
      for (int q=0;q<4;++q) gload16(A + kb + aSrc[q], &Af[nb][aDst[q]]);
      gload16(Wt + kb + rb0, lb0[nb]);
      gload16(Wt + kb + rb1, lb1[nb]);
    }
    bf16x8 af[4], bfr[4];
    #pragma unroll
    for (int mi=0;mi<4;++mi){
      const int rA = wm + mi*16 + lr;
      const int p0 = (2*lg)     ^ (rA & 7);
      const int p1 = (2*lg + 1) ^ (rA & 7);
      f32x4 lo = *reinterpret_cast<const f32x4*>(&Af[cur][rA*32 + p0*4]);
      f32x4 hi = *reinterpret_cast<const f32x4*>(&Af[cur][rA*32 + p1*4]);
      unsigned u0,u1,u2,u3;
      asm("v_cvt_pk_bf16_f32 %0, %1, %2" : "=v"(u0) : "v"(lo[0]), "v"(lo[1]));
      asm("v_cvt_pk_bf16_f32 %0, %1, %2" : "=v"(u1) : "v"(lo[2]), "v"(lo[3]));
      asm("v_cvt_pk_bf16_f32 %0, %1, %2" : "=v"(u2) : "v"(hi[0]), "v"(hi[1]));
      asm("v_cvt_pk_bf16_f32 %0, %1, %2" : "=v"(u3) : "v"(hi[2]), "v"(hi[3]));
      uint4 uu = make_uint4(u0,u1,u2,u3);
      af[mi] = __builtin_bit_cast(bf16x8, uu);
    }
    #pragma unroll
    for (int ni=0;ni<4;++ni)
      bfr[ni] = *reinterpret_cast<const bf16x8*>(&Bs[cur][(wn+ni*16+lr)*32 + cswz]);
    #pragma unroll
    for (int mi=0;mi<4;++mi)
      #pragma unroll
      for (int ni=0;ni<4;++ni)
        acc[mi][ni] = __builtin_amdgcn_mfma_f32_16x16x32_bf16(af[mi], bfr[ni], acc[mi][ni], 0, 0, 0);
  }

  float bs[4];
  #pragma unroll
  for (int ni=0;ni<4;++ni) bs[ni] = bias[n0 + wn + ni*16 + lr];
  #pragma unroll
  for (int mi=0;mi<4;++mi){
    #pragma unroll
    for (int i=0;i<4;++i){
      const int row = m0 + wm + mi*16 + lg*4 + i;
      if (row >= M) continue;
      #pragma unroll
      for (int ni=0;ni<4;++ni){
        const int col = n0 + wn + ni*16 + lr;
        Cb[(size_t)row*256 + col] = f2bf(acc[mi][ni][i] + bs[ni]);
      }
    }
  }
}

// ---------------- bf16 MFMA GEMM, 64x64 tile, BK=64 ----------------
// EPI: 0 = f32 out, 1 = bf16 out, 2 = QK headwise bf16, 3 = V^T head layout
template<int EPI>
__global__ __launch_bounds__(256) void k_gemm64(
    const unsigned short* __restrict__ A, int lda,
    const unsigned short* __restrict__ Wt,
    const float* __restrict__ bias,
    float* __restrict__ Cf, unsigned short* __restrict__ Cb, int ldc,
    int M, int N, int K, int relu)
{
  __shared__ unsigned short As[2][4096];
  __shared__ unsigned short Bs[2][4096];
  const int t = threadIdx.x;
  const int lin = xcd_swz(blockIdx.y*gridDim.x + blockIdx.x, gridDim.x*gridDim.y);
  const int bx = lin % gridDim.x, by = lin / gridDim.x;
  const int m0 = by * 64;
  const int n0 = bx * 64;
  const int w = t >> 6, lane = t & 63;
  const int lr = lane & 15, lg = lane >> 4;
  const int wm = (w & 1) * 32, wn = (w >> 1) * 32;

  const int c0 = w*64 + lane;
  const int c1 = 256 + w*64 + lane;
  const int r0c = c0 >> 3, s0c = ((c0 & 7) ^ (r0c & 7)) << 3;
  const int r1c = c1 >> 3, s1c = ((c1 & 7) ^ (r1c & 7)) << 3;
  const size_t a0 = (size_t)(m0 + r0c)*lda + s0c;
  const size_t a1 = (size_t)(m0 + r1c)*lda + s1c;
  const size_t b0 = (size_t)(n0 + r0c)*K + s0c;
  const size_t b1 = (size_t)(n0 + r1c)*K + s1c;
  const int d0 = w*512, d1 = 2048 + w*512;

  f32x4 acc[2][2];
  acc[0][0]=acc[0][1]=acc[1][0]=acc[1][1]=(f32x4){0.f,0.f,0.f,0.f};

  gload16(A + a0, &As[0][d0]);  gload16(A + a1, &As[0][d1]);
  gload16(Wt + b0, &Bs[0][d0]); gload16(Wt + b1, &Bs[0][d1]);
  const int nt = K >> 6;
  for (int ks = 0; ks < nt; ++ks) {
    const int cur = ks & 1;
    __syncthreads();
    if (ks + 1 < nt) {
      const int kb = (ks + 1) << 6;
      const int nb = cur ^ 1;
      gload16(A + kb + a0, &As[nb][d0]);  gload16(A + kb + a1, &As[nb][d1]);
      gload16(Wt + kb + b0, &Bs[nb][d0]); gload16(Wt + kb + b1, &Bs[nb][d1]);
    }
    bf16x8 af[2][2], bfr[2][2];
    #pragma unroll
    for (int mi=0;mi<2;++mi){
      const int r = wm + mi*16 + lr;
      #pragma unroll
      for (int kk=0;kk<2;++kk){
        const int ch = ((kk*4 + lg) ^ (r & 7)) << 3;
        af[mi][kk] = *reinterpret_cast<const bf16x8*>(&As[cur][r*64 + ch]);
      }
    }
    #pragma unroll
    for (int ni=0;ni<2;++ni){
      const int r = wn + ni*16 + lr;
      #pragma unroll
      for (int kk=0;kk<2;++kk){
        const int ch = ((kk*4 + lg) ^ (r & 7)) << 3;
        bfr[ni][kk] = *reinterpret_cast<const bf16x8*>(&Bs[cur][r*64 + ch]);
      }
    }
    #pragma unroll
    for (int kk=0;kk<2;++kk)
      #pragma unroll
      for (int mi=0;mi<2;++mi)
        #pragma unroll
        for (int ni=0;ni<2;++ni)
          acc[mi][ni] = __builtin_amdgcn_mfma_f32_16x16x32_bf16(af[mi][kk], bfr[ni][kk], acc[mi][ni], 0, 0, 0);
  }

  float bs[2];
  bs[0] = bias[n0 + wn + lr];
  bs[1] = bias[n0 + wn + 16 + lr];
  if (EPI == 3) {
    #pragma unroll
    for (int mi=0;mi<2;++mi){
      const int rowb = m0 + wm + mi*16 + lg*4;
      #pragma unroll
      for (int ni=0;ni<2;++ni){
        const int colb = n0 + wn + ni*16 + lr;
        const int bh = (rowb >> 10)*8 + (colb >> 5);
        const int d = colb & 31;
        ushort4 pkv;
        pkv.x = f2bf(acc[mi][ni][0] + bs[ni]);
        pkv.y = f2bf(acc[mi][ni][1] + bs[ni]);
        pkv.z = f2bf(acc[mi][ni][2] + bs[ni]);
        pkv.w = f2bf(acc[mi][ni][3] + bs[ni]);
        *reinterpret_cast<ushort4*>(Cb + (size_t)bh*32768 + (size_t)d*1024 + (rowb & 1023)) = pkv;
      }
    }
    return;
  }
  #pragma unroll
  for (int mi=0;mi<2;++mi){
    #pragma unroll
    for (int i=0;i<4;++i){
      const int row = m0 + wm + mi*16 + lg*4 + i;
      #pragma unroll
      for (int ni=0;ni<2;++ni){
        const int col = n0 + wn + ni*16 + lr;
        float v = acc[mi][ni][i] + bs[ni];
        if (relu) v = fmaxf(v, 0.f);
        if (EPI == 0) {
          Cf[(size_t)row*ldc + col] = v;
        } else if (EPI == 1) {
          Cb[(size_t)row*ldc + col] = f2bf(v);
        } else {
          const int ch = col & 255;
          const int sel = col >> 8;                       // 0=Q, 1=K
          const int bh = (row >> 10)*8 + (ch >> 5);
          Cb[(size_t)sel*2097152 + (size_t)bh*32768 + (size_t)(row & 1023)*32 + (ch & 31)] = f2bf(v);
        }
      }
    }
  }
}

// ---------------- fused GEMM(N=256) + bias + residual + LayerNorm ----------------
__global__ __launch_bounds__(256) void k_gemm_ln(
    const unsigned short* __restrict__ A, int lda,
    const unsigned short* __restrict__ Wt,
    const float* __restrict__ bias,
    const float* __restrict__ X,
    const float* __restrict__ g, const float* __restrict__ be,
    float* __restrict__ out,
    unsigned short* __restrict__ ab,
    const float* __restrict__ qo, const float* __restrict__ rp,
    const float* __restrict__ rf, unsigned short* __restrict__ dqb,
    int K)
{
  __shared__ unsigned short As[2][1024];
  __shared__ unsigned short Bs[2][16384];
  __shared__ float part[4][16][2];
  const int t = threadIdx.x;
  const int w = t >> 6, lane = t & 63;
  const int lr = lane & 15, lg = lane >> 4;
  const int m0 = xcd_swz(blockIdx.x, gridDim.x) * 16;

  const int ar = t >> 3, ac = t & 7;
  const size_t aSrc = (size_t)(m0 + ar)*lda + ((ac ^ (ar & 7)) << 3);
  size_t bSrc[8];
  #pragma unroll
  for (int q=0;q<8;++q){
    const int c = q*256 + t;
    const int br = c >> 3, bc = c & 7;
    bSrc[q] = (size_t)br*K + ((bc ^ (br & 7)) << 3);
  }

  f32x4 acc[4];
  #pragma unroll
  for (int ni=0;ni<4;++ni) acc[ni] = (f32x4){0.f,0.f,0.f,0.f};

  if (w < 2) gload16(A + aSrc, &As[0][(w<<9)]);
  #pragma unroll
  for (int q=0;q<8;++q) gload16(Wt + bSrc[q], &Bs[0][q*2048 + (w<<9)]);

  const int nt = K >> 6;
  for (int ks = 0; ks < nt; ++ks) {
    const int cur = ks & 1;
    __syncthreads();
    if (ks + 1 < nt) {
      const int kb = (ks + 1) << 6;
      const int nb = cur ^ 1;
      if (w < 2) gload16(A + kb + aSrc, &As[nb][(w<<9)]);
      #pragma unroll
      for (int q=0;q<8;++q) gload16(Wt + kb + bSrc[q], &Bs[nb][q*2048 + (w<<9)]);
    }
    bf16x8 af[2];
    #pragma unroll
    for (int kk=0;kk<2;++kk){
      const int ch = ((kk*4 + lg) ^ (lr & 7)) << 3;
      af[kk] = *reinterpret_cast<const bf16x8*>(&As[cur][lr*64 + ch]);
    }
    #pragma unroll
    for (int ni=0;ni<4;++ni){
      const int r = w*64 + ni*16 + lr;
      #pragma unroll
      for (int kk=0;kk<2;++kk){
        const int ch = ((kk*4 + lg) ^ (r & 7)) << 3;
        bf16x8 bfv = *reinterpret_cast<const bf16x8*>(&Bs[cur][r*64 + ch]);
        acc[ni] = __builtin_amdgcn_mfma_f32_16x16x32_bf16(af[kk], bfv, acc[ni], 0, 0, 0);
      }
    }
  }

  float v[4][4];
  int colv[4];
  #pragma unroll
  for (int ni=0;ni<4;++ni) colv[ni] = w*64 + ni*16 + lr;
  #pragma unroll
  for (int ni=0;ni<4;++ni){
    const float bsv = bias[colv[ni]];
    #pragma unroll
    for (int i=0;i<4;++i){
      const int row = m0 + lg*4 + i;
      v[ni][i] = acc[ni][i] + bsv + X[(size_t)row*256 + colv[ni]];
    }
  }
  #pragma unroll
  for (int i=0;i<4;++i){
    float s1 = v[0][i]+v[1][i]+v[2][i]+v[3][i];
    float s2 = v[0][i]*v[0][i]+v[1][i]*v[1][i]+v[2][i]*v[2][i]+v[3][i]*v[3][i];
    #pragma unroll
    for (int o=1;o<16;o<<=1){ s1 += __shfl_xor(s1,o,64); s2 += __shfl_xor(s2,o,64); }
    if (lr == 0){ part[w][lg*4+i][0] = s1; part[w][lg*4+i][1] = s2; }
  }
  __syncthreads();
  #pragma unroll
  for (int i=0;i<4;++i){
    const int rl = lg*4 + i;
    const float S1 = part[0][rl][0]+part[1][rl][0]+part[2][rl][0]+part[3][rl][0];
    const float S2 = part[0][rl][1]+part[1][rl][1]+part[2][rl][1]+part[3][rl][1];
    const float mean = S1 * 0.00390625f;
    const float var  = S2 * 0.00390625f - mean*mean;
    const float rstd = rsqrtf(var + 1e-5f);
    const size_t row = m0 + rl;
    #pragma unroll
    for (int ni=0;ni<4;++ni){
      const int col = colv[ni];
      const float o = (v[ni][i]-mean)*rstd*g[col] + be[col];
      out[row*256 + col] = o;
      if (ab) ab[row*256 + col] = f2bf(o);
      if (dqb) {
        const float e = qo[row*256+col] + rp[row*256+col] + rf[row*256+col];
        dqb[row*256 + col] = f2bf(o + e);
      }
    }
  }
}

// ---------------- MFMA flash attention, LDS-staged double-buffered, XCD-swizzled ----------------
__global__ __launch_bounds__(256) void k_attn2(
    const unsigned short* __restrict__ Qbf,
    const unsigned short* __restrict__ Kbf,
    const unsigned short* __restrict__ Vtb,
    const float* __restrict__ biasf,
    unsigned short* __restrict__ Ob)
{
  __shared__ unsigned short Klds[2][2048];
  __shared__ unsigned short Vlds[2][2048];
  __shared__ float Blds[1024];
  const int t = threadIdx.x;
  const int wv = t >> 6, lane = t & 63;
  const int lin = xcd_swz(blockIdx.y*gridDim.x + blockIdx.x, gridDim.x*gridDim.y);
  const int bx = lin % gridDim.x, by = lin / gridDim.x;
  const int qt = bx * 4 + wv;
  const int bh = by;
  const int b = bh >> 3;
  const int q0 = qt << 4;
  const int lr = lane & 15, lg = lane >> 4;

  bf16x8 qf = *reinterpret_cast<const bf16x8*>(
      Qbf + (size_t)bh*32768 + (size_t)(q0 + lr)*32 + lg*8);

  *reinterpret_cast<float4*>(&Blds[t*4]) =
      *reinterpret_cast<const float4*>(biasf + b*1024 + t*4);

  const unsigned short* Kg = Kbf + (size_t)bh*32768;
  const unsigned short* Vg = Vtb + (size_t)bh*32768;

  const int kRow   = lane >> 2;
  const int kChunk = (lane & 3) ^ (kRow & 3);
  const size_t kSrc = (size_t)(wv*16 + kRow)*32 + (kChunk<<3);
  const int vDim   = lane >> 3;
  const int vChunk = (lane & 7) ^ vDim;
  const size_t vSrc = (size_t)(wv*8 + vDim)*1024 + (vChunk<<3);
  unsigned short* kDst[2] = { &Klds[0][wv<<9], &Klds[1][wv<<9] };
  unsigned short* vDst[2] = { &Vlds[0][wv<<9], &Vlds[1][wv<<9] };

  gload16(Kg + kSrc, kDst[0]);
  gload16(Vg + vSrc, vDst[0]);
  __syncthreads();

  f32x4 acc0 = {0.f,0.f,0.f,0.f}, acc1 = {0.f,0.f,0.f,0.f};
  float m_run = -1e30f, l_run = 0.f;
  const float Cs = 0.17677669529663687f * 1.4426950408889634f;
  const int kswz = (lg ^ (lr & 3)) << 3;

  for (int kt = 0; kt < 16; ++kt) {
    const int cur = kt & 1;
    if (kt + 1 < 16) {
      const size_t k0n = (size_t)(kt + 1) << 6;
      gload16(Kg + k0n*32 + kSrc, kDst[cur^1]);
      gload16(Vg + k0n    + vSrc, vDst[cur^1]);
    }
    f32x4 st[4];
    __builtin_amdgcn_s_setprio(1);
    #pragma unroll
    for (int j=0;j<4;++j){
      bf16x8 kf = *reinterpret_cast<const bf16x8*>(&Klds[cur][(16*j + lr)*32 + kswz]);
      f32x4 z = {0.f,0.f,0.f,0.f};
      st[j] = __builtin_amdgcn_mfma_f32_16x16x32_bf16(kf, qf, z, 0, 0, 0);
    }
    __builtin_amdgcn_s_setprio(0);
    const int k0 = kt << 6;
    float s[16];
    #pragma unroll
    for (int j=0;j<4;++j){
      float4 bv = *reinterpret_cast<const float4*>(&Blds[k0 + 16*j + lg*4]);
      s[4*j+0] = fmaf(st[j][0], Cs, bv.x);
      s[4*j+1] = fmaf(st[j][1], Cs, bv.y);
      s[4*j+2] = fmaf(st[j][2], Cs, bv.z);
      s[4*j+3] = fmaf(st[j][3], Cs, bv.w);
    }
    float mc = fmaxf(fmaxf(fmaxf(s[0],s[1]),fmaxf(s[2],s[3])),
                     fmaxf(fmaxf(s[4],s[5]),fmaxf(s[6],s[7])));
    float mc2 = fmaxf(fmaxf(fmaxf(s[8],s[9]),fmaxf(s[10],s[11])),
                      fmaxf(fmaxf(s[12],s[13]),fmaxf(s[14],s[15])));
    mc = fmaxf(mc, mc2);
    mc = fmaxf(mc, __shfl_xor(mc, 16, 64));
    mc = fmaxf(mc, __shfl_xor(mc, 32, 64));
    if (!__all(mc <= m_run + 8.f)) {
      float m_new = fmaxf(m_run, mc);
      float sc = fexp2(m_run - m_new);
      l_run *= sc;
      m_run = m_new;
      float sc0 = __shfl(sc, lg*4+0, 64);
      float sc1 = __shfl(sc, lg*4+1, 64);
      float sc2 = __shfl(sc, lg*4+2, 64);
      float sc3 = __shfl(sc, lg*4+3, 64);
      acc0[0]*=sc0; acc0[1]*=sc1; acc0[2]*=sc2; acc0[3]*=sc3;
      acc1[0]*=sc0; acc1[1]*=sc1; acc1[2]*=sc2; acc1[3]*=sc3;
    }
    float p[16];
    #pragma unroll
    for (int i=0;i<16;++i) p[i] = fexp2(s[i] - m_run);
    float ps = 0.f;
    #pragma unroll
    for (int i=0;i<16;++i) ps += p[i];
    ps += __shfl_xor(ps, 16, 64);
    ps += __shfl_xor(ps, 32, 64);
    l_run += ps;
    bf16x4 pb[4];
    #pragma unroll
    for (int j=0;j<4;++j){
      unsigned lo, hi;
      asm("v_cvt_pk_bf16_f32 %0, %1, %2" : "=v"(lo) : "v"(p[4*j+0]), "v"(p[4*j+1]));
      asm("v_cvt_pk_bf16_f32 %0, %1, %2" : "=v"(hi) : "v"(p[4*j+2]), "v"(p[4*j+3]));
      uint2 u = make_uint2(lo, hi);
      pb[j] = __builtin_bit_cast(bf16x4, u);
    }
    __builtin_amdgcn_s_setprio(1);
    #pragma unroll
    for (int j=0;j<4;++j){
      const int coff = (((2*j + (lg>>1)) ^ (lr & 7)) << 3) + ((lg & 1) << 2);
      bf16x4 v0 = *reinterpret_cast<const bf16x4*>(&Vlds[cur][lr*64 + coff]);
      bf16x4 v1 = *reinterpret_cast<const bf16x4*>(&Vlds[cur][(16+lr)*64 + coff]);
      acc0 = mfma16x16(pb[j], v0, acc0);
      acc1 = mfma16x16(pb[j], v1, acc1);
    }
    __builtin_amdgcn_s_setprio(0);
    __syncthreads();
  }
  float li[4];
  #pragma unroll
  for (int i=0;i<4;++i) li[i] = 1.f / __shfl(l_run, lg*4+i, 64);
  const int h = bh & 7;
  unsigned short* orow = Ob + (size_t)(b*1024 + q0)*256 + h*32;
  #pragma unroll
  for (int i=0;i<4;++i){
    orow[(size_t)(lg*4+i)*256 + lr]      = f2bf(acc0[i]*li[i]);
    orow[(size_t)(lg*4+i)*256 + 16 + lr] = f2bf(acc1[i]*li[i]);
  }
}

// ---------------- deform: fused weights + gather (one block per bq) ----------------
__global__ __launch_bounds__(256) void k_dgather2(
    const unsigned short* __restrict__ vproj,
    const float* __restrict__ IJ,
    const float* __restrict__ refp,
    unsigned short* __restrict__ outb)
{
  __shared__ int   ilds[8][12][4];
  __shared__ float wlds[8][12][4];
  const int t = threadIdx.x;
  const int bq = blockIdx.x;
  const int h = t >> 5;
  const int p = t & 31;
  if (p < 12) {
    const float* al = IJ + (size_t)bq*384 + 192 + h*12;
    float lg[12];
    float mx = -INFINITY;
    #pragma unroll
    for (int i=0;i<12;++i){ lg[i] = al[i]; mx = fmaxf(mx, lg[i]); }
    float se = 0.f;
    #pragma unroll
    for (int i=0;i<12;++i) se += __expf(lg[i]-mx);
    const float aw = __expf(lg[p]-mx) / se;
    const float rx = refp[(size_t)bq*2+0], ry = refp[(size_t)bq*2+1];
    const float ox = IJ[(size_t)bq*384 + h*24 + 2*p];
    const float oy = IJ[(size_t)bq*384 + h*24 + 2*p + 1];
    const int l = p >> 2;
    const int WW[3]={100,50,25}, SS[3]={0,10000,12500};
    const int Wi = WW[l], Hi = WW[l], s0 = SS[l];
    const float Wf = (float)Wi, Hf = (float)Hi;
    const float x = (rx + ox/Wf)*Wf - 0.5f;
    const float y = (ry + oy/Hf)*Hf - 0.5f;
    const float x0f = floorf(x), y0f = floorf(y);
    const float wx = x - x0f, wy = y - y0f;
    const int x0 = (int)x0f, y0 = (int)y0f;
    const int xs0 = min(max(x0,0),Wi-1),   xs1 = min(max(x0+1,0),Wi-1);
    const int ys0 = min(max(y0,0),Hi-1),   ys1 = min(max(y0+1,0),Hi-1);
    const bool vx0 = (x0>=0)&&(x0<Wi),     vx1 = (x0+1>=0)&&(x0+1<Wi);
    const bool vy0 = (y0>=0)&&(y0<Hi),     vy1 = (y0+1>=0)&&(y0+1<Hi);
    const int vb = (bq >> 10) * LIN_;
    ilds[h][p][0] = vb + s0 + ys0*Wi + xs0;
    ilds[h][p][1] = vb + s0 + ys0*Wi + xs1;
    ilds[h][p][2] = vb + s0 + ys1*Wi + xs0;
    ilds[h][p][3] = vb + s0 + ys1*Wi + xs1;
    wlds[h][p][0] = (vy0&&vx0)? (1.f-wy)*(1.f-wx)*aw : 0.f;
    wlds[h][p][1] = (vy0&&vx1)? (1.f-wy)*wx*aw       : 0.f;
    wlds[h][p][2] = (vy1&&vx0)? wy*(1.f-wx)*aw       : 0.f;
    wlds[h][p][3] = (vy1&&vx1)? wy*wx*aw             : 0.f;
  }
  __syncthreads();
  const int col = t;
  float acc = 0.f;
  #pragma unroll
  for (int pt=0; pt<12; ++pt){
    acc = fmaf(wlds[h][pt][0], bf2f(vproj[(size_t)ilds[h][pt][0]*256 + col]), acc);
    acc = fmaf(wlds[h][pt][1], bf2f(vproj[(size_t)ilds[h][pt][1]*256 + col]), acc);
    acc = fmaf(wlds[h][pt][2], bf2f(vproj[(size_t)ilds[h][pt][2]*256 + col]), acc);
    acc = fmaf(wlds[h][pt][3], bf2f(vproj[(size_t)ilds[h][pt][3]*256 + col]), acc);
  }
  outb[(size_t)bq*256 + col] = f2bf(acc);
}

extern "C" void kernel_launch(void* const* d_in, const int* in_sizes, int n_in,
                              void* d_out, int out_size, void* d_ws, size_t ws_size,
                              hipStream_t stream)
{
  const float* qe      = (const float*)d_in[0];
  const unsigned char* qmask = (const unsigned char*)d_in[1];
  const float* qo      = (const float*)d_in[2];
  const float* values  = (const float*)d_in[3];
  const float* refp    = (const float*)d_in[4];
  const float* rp      = (const float*)d_in[5];
  const float* rf      = (const float*)d_in[6];
  const float* sa_in_w = (const float*)d_in[10];
  const float* sa_in_b = (const float*)d_in[11];
  const float* sa_out_w= (const float*)d_in[12];
  const float* sa_out_b= (const float*)d_in[13];
  const float* sa_ln1_g= (const float*)d_in[14];
  const float* sa_ln1_b= (const float*)d_in[15];
  const float* sa_l1_w = (const float*)d_in[16];
  const float* sa_l1_b = (const float*)d_in[17];
  const float* sa_l2_w = (const float*)d_in[18];
  const float* sa_l2_b = (const float*)d_in[19];
  const float* sa_ln2_g= (const float*)d_in[20];
  const float* sa_ln2_b= (const float*)d_in[21];
  const float* da_val_w= (const float*)d_in[22];
  const float* da_val_b= (const float*)d_in[23];
  const float* da_off_w= (const float*)d_in[24];
  const float* da_off_b= (const float*)d_in[25];
  const float* da_att_w= (const float*)d_in[26];
  const float* da_att_b= (const float*)d_in[27];
  const float* da_out_w= (const float*)d_in[28];
  const float* da_out_b= (const float*)d_in[29];
  const float* ln1_g   = (const float*)d_in[30];
  const float* ln1_b   = (const float*)d_in[31];
  const float* ff1_w   = (const float*)d_in[32];
  const float* ff1_b   = (const float*)d_in[33];
  const float* ff2_w   = (const float*)d_in[34];
  const float* ff2_b   = (const float*)d_in[35];
  const float* ln2_g   = (const float*)d_in[36];
  const float* ln2_b   = (const float*)d_in[37];

  float* Wk = (float*)d_ws;
  const size_t MEG = 1u<<20;
  float* A   = Wk;                                       // [0,2M)
  unsigned short* Ab   = (unsigned short*)(Wk + 4*MEG);  // [4M,5M)
  unsigned short* hidb = (unsigned short*)(Wk + 5*MEG);  // [5M,9M)
  unsigned short* WT   = (unsigned short*)(Wk + 9*MEG);  // [9M,10M)
  unsigned short* qb   = (unsigned short*)(Wk + 10*MEG); // [10M,11M)
  unsigned short* srcb = (unsigned short*)(Wk + 11*MEG); // [11M,12M)
  unsigned short* Qbf  = (unsigned short*)(Wk + 12*MEG); // [12M,13M)
  unsigned short* Kbf  = (unsigned short*)(Wk + 13*MEG); // [13M,14M) (= Qbf+2097152)
  unsigned short* Vtb  = (unsigned short*)(Wk + 15*MEG); // [15M,16M)
  unsigned short* aob  = (unsigned short*)(Wk + 16*MEG); // [16M,17M)
  // deform phase (reuses attn regions after they're dead)
  unsigned short* dqb  = (unsigned short*)(Wk + 10*MEG); // [10M,11M)
  float* IJ = Wk + 12*MEG;                               // 8192x384 f32
  unsigned short* Hb = (unsigned short*)(Wk + 37*MEG);   // vproj bf16
  unsigned short* dG = (unsigned short*)(Wk + 51*MEG);   // gather out bf16
  float* biasf  = Wk + 52*MEG;                           // 8192 f32
  float* biasoa = Wk + 52*MEG + 8192;                    // 384 f32

  unsigned short* sa_inT  = WT;
  unsigned short* sa_outT = WT + 196608;
  unsigned short* sa_l1T  = WT + 262144;
  unsigned short* sa_l2T  = WT + 524288;
  unsigned short* da_valT = WT + 786432;
  unsigned short* da_outT = WT + 851968;
  unsigned short* ff1T    = WT + 917504;
  unsigned short* ff2T    = WT + 1179648;
  unsigned short* offattT = WT + 1441792;                // 384x256 (rows 288+ garbage, never read)

  WPack wp_;
  wp_.e[0] = { sa_in_w, sa_inT, 256, 768 };
  wp_.e[1] = { sa_out_w, sa_outT, 256, 256 };
  wp_.e[2] = { sa_l1_w, sa_l1T, 256, 1024 };
  wp_.e[3] = { sa_l2_w, sa_l2T, 1024, 256 };
  wp_.e[4] = { da_val_w, da_valT, 256, 256 };
  wp_.e[5] = { da_out_w, da_outT, 256, 256 };
  wp_.e[6] = { ff1_w, ff1T, 256, 1024 };
  wp_.e[7] = { ff2_w, ff2T, 1024, 256 };
  wp_.e[8] = { da_off_w, offattT, 256, 192 };
  wp_.e[9] = { da_att_w, offattT + 192*256, 256, 96 };

  dim3 blk(256);
  k_wtcvt<<<dim3(64,10), blk, 0, stream>>>(wp_);
  k_prep<<<2048, blk, 0, stream>>>((const float4*)qe,(const float4*)rf,
                                   (const float4*)qo,(const float4*)rp,
                                   qmask, da_off_b, da_att_b,
                                   (float4*)A,(uint2*)srcb,(uint2*)qb,
                                   biasf, biasoa);
  k_gemm64<2><<<dim3(8,128), blk, 0, stream>>>(qb,256, sa_inT, sa_in_b, nullptr,Qbf,0, 8192,512,256, 0);
  k_gemm64<3><<<dim3(4,128), blk, 0, stream>>>(srcb,256, sa_inT+512*256, sa_in_b+512, nullptr,Vtb,0, 8192,256,256, 0);
  k_attn2<<<dim3(16,64), blk, 0, stream>>>(Qbf, Kbf, Vtb, biasf, aob);
  k_gemm_ln<<<512, blk, 0, stream>>>(aob,256, sa_outT, sa_out_b, A,
                                     sa_ln1_g, sa_ln1_b, A, Ab,
                                     nullptr, nullptr, nullptr, nullptr, 256);
  k_gemm_bf<true><<<dim3(8,64), blk, 0, stream>>>(Ab,256, sa_l1T, sa_l1_b, nullptr,hidb,1024, 8192,1024,256, 1);
  k_gemm_ln<<<512, blk, 0, stream>>>(hidb,1024, sa_l2T, sa_l2_b, A,
                                     sa_ln2_g, sa_ln2_b, A, Ab,
                                     qo, rp, rf, dqb, 1024);
  k_gemm64<0><<<dim3(6,128), blk, 0, stream>>>(dqb,256, offattT, biasoa, IJ,nullptr,384, 8192,384,256, 0);
  k_gemm_vp<<<dim3(2,821), blk, 0, stream>>>(values, da_valT, da_val_b, Hb, 105000);
  k_dgather2<<<8192, blk, 0, stream>>>(Hb, IJ, refp, dG);
  k_gemm_ln<<<512, blk, 0, stream>>>(dG,256, da_outT, da_out_b, A,
                                     ln1_g, ln1_b, A, Ab,
                                     nullptr, nullptr, nullptr, nullptr, 256);
  k_gemm_bf<true><<<dim3(8,64), blk, 0, stream>>>(Ab,256, ff1T, ff1_b, nullptr,hidb,1024, 8192,1024,256, 1);
  k_gemm_ln<<<512, blk, 0, stream>>>(hidb,1024, ff2T, ff2_b, A,
                                     ln2_g, ln2_b, (float*)d_out, nullptr,
                                     nullptr, nullptr, nullptr, nullptr, 1024);
}